// Round 16
// baseline (129.528 us; speedup 1.0000x reference)
//
#include <hip/hip_runtime.h>
#include <math.h>

#define HI 256
#define WI 256
#define NIMG 128          // B*S
#define NP 68             // landmarks
#define NT 16             // 4x4 tiles of 16x16 outputs per 64x64 heatmap
#define NPAIR 120         // B*(S-1)
#define K_LK 289          // 17x17 window
#define NCONVB (NT * NIMG)   // 2048 conv blocks (gray fused in)
#define NTASK (2 * NPAIR * NP)   // 16320 LK tasks
// LK LDS patch row stride (floats). R15 had 28 (==28 mod 32): the 4 sample
// rows landed on banks {0,28,24,20} -> several 4-way conflicts (1.22e7
// conflict cycles/dispatch ~ 20us). 40 (==8 mod 32) tiles rows at {0,8,16,24}:
// 28 banks 2-way (free, m136), 4 banks 3-way. 160B rows stay 16B-aligned.
#define PSTR 40

typedef float f4v __attribute__((ext_vector_type(4)));
typedef float f2v __attribute__((ext_vector_type(2)));
typedef f4v __attribute__((aligned(4))) uf4;
typedef f2v __attribute__((aligned(4))) uf2;

typedef short bfv8 __attribute__((ext_vector_type(8)));   // 8 bf16 (MFMA frag)
typedef bfv8 __attribute__((aligned(8))) ubfv8;           // 8B-aligned LDS view

#define WBF_ELEMS (3 * 8 * 80 * 8)   // bf16 weight image [c][ky0..7][f0..79][kx0..7]

__device__ __forceinline__ short f2bf(float x) {
    unsigned u = __builtin_bit_cast(unsigned, x);
    u += 0x7fffu + ((u >> 16) & 1u);          // round-to-nearest-even
    return (short)(u >> 16);
}
__device__ __forceinline__ unsigned pk2(float lo, float hi) {
    return (unsigned)(unsigned short)f2bf(lo) | ((unsigned)(unsigned short)f2bf(hi) << 16);
}

// ---- DPP wave-64 sum; lane 63 holds the total (6 VALU ops, no LDS round-trip)
#define DPPA(ctrl, rm)                                                          \
    {                                                                           \
        int m_ = __builtin_amdgcn_update_dpp(0, __builtin_bit_cast(int, x),     \
                                             ctrl, rm, 0xf, true);              \
        x += __builtin_bit_cast(float, m_);                                     \
    }
__device__ __forceinline__ float wave_sum64(float x) {
    DPPA(0x111, 0xf)   // row_shr:1
    DPPA(0x112, 0xf)   // row_shr:2
    DPPA(0x114, 0xf)   // row_shr:4
    DPPA(0x118, 0xf)   // row_shr:8
    DPPA(0x142, 0xa)   // row_bcast:15 -> rows 1,3
    DPPA(0x143, 0xc)   // row_bcast:31 -> rows 2,3
    return x;          // lane 63 = total
}
__device__ __forceinline__ float rl63(float x) {
    return __builtin_bit_cast(float,
        __builtin_amdgcn_readlane(__builtin_bit_cast(int, x), 63));
}

// ---------------------------------------------------------------------------
// Kernel 0: weight prep -> bf16 [c][ky(8)][p(80)][kx(8)], pads zero. Grid 16.
// ---------------------------------------------------------------------------
__global__ __launch_bounds__(256) void k_wprep(const float* __restrict__ dw,
                                               short* __restrict__ wbf) {
    for (int ii = blockIdx.x * 256 + threadIdx.x; ii < WBF_ELEMS / 2;
         ii += 16 * 256) {
        int s0 = 2 * ii;                 // short index, kx = s0 & 7 (even)
        int kx = s0 & 7;
        int rest = s0 >> 3;              // (c*8+ky)*80 + p
        int p = rest % 80;
        int cky = rest / 80;             // c*8+ky
        int c = cky >> 3;
        int ky = cky & 7;
        unsigned lo = 0, hi = 0;
        if (ky < 7 && p < NP) {
            const float* wp = dw + p * 147 + (c * 7 + ky) * 7;
            lo = (unsigned short)f2bf(wp[kx]);
            if (kx + 1 < 7) hi = (unsigned short)f2bf(wp[kx + 1]);
        }
        ((int*)wbf)[ii] = (int)(lo | (hi << 16));
    }
}

// ---------------------------------------------------------------------------
// Kernel 1: conv 7x7/s4 MFMA + softmax stats, WITH gray fused into staging.
// ---------------------------------------------------------------------------
#define IN_RS 72                     // LDS input row stride (shorts), 144B
__global__ __launch_bounds__(256, 3) void k_convgray(const float* __restrict__ in,
                                                     const short* __restrict__ wbf,
                                                     float* __restrict__ stats,
                                                     float* __restrict__ gray) {
    const int bid = blockIdx.x;
    const int tile = bid & 15;
    const int n = bid >> 4;
    const int ty0 = (tile >> 2) * 16;
    const int tx0 = (tile & 3) * 16;
    const int tid = threadIdx.x;
    const int w = __builtin_amdgcn_readfirstlane(tid >> 6);   // wave: rows 4w..4w+3
    const int lane = tid & 63;
    const int lx = lane & 15;        // pixel x (A) / filter (B)
    const int lg = lane >> 4;        // k-group

    __shared__ short in_lds[3 * 68 * IN_RS];    // 29376 B bf16, x = C-(4tx0-1)
    __shared__ float part_m[4][80];
    __shared__ float Mf[80];
    __shared__ float part_s[4][80], part_sx[4][80], part_sy[4][80];

    const float* img = in + (size_t)n * 3 * HI * WI;
    const float kk = 1.0f / 3.0f;

    // ---- pass 1: main cols x=1..64, 3 channels/row, + gray core write ----
    {
        const int q = lane & 15;
        const int rsub = lane >> 4;
#pragma unroll
        for (int rr = 0; rr < 5; ++rr) {
            int r = rr * 16 + w * 4 + rsub;       // 0..79
            if (r < 68) {
                int R = 4 * ty0 - 1 + r;
                f4v v0 = (f4v)0.0f, v1 = (f4v)0.0f, v2 = (f4v)0.0f;
                if ((unsigned)R < HI) {
                    const float* s = img + (size_t)R * WI + 4 * tx0 + 4 * q;
                    v0 = *(const f4v*)(s);
                    v1 = *(const f4v*)(s + HI * WI);
                    v2 = *(const f4v*)(s + 2 * HI * WI);
                }
                short* r0 = &in_lds[r * IN_RS];
                r0[4 * q + 1] = f2bf(v0.x);
                *(int*)&r0[4 * q + 2] = (int)pk2(v0.y, v0.z);
                r0[4 * q + 4] = f2bf(v0.w);
                short* r1 = &in_lds[(68 + r) * IN_RS];
                r1[4 * q + 1] = f2bf(v1.x);
                *(int*)&r1[4 * q + 2] = (int)pk2(v1.y, v1.z);
                r1[4 * q + 4] = f2bf(v1.w);
                short* r2 = &in_lds[(136 + r) * IN_RS];
                r2[4 * q + 1] = f2bf(v2.x);
                *(int*)&r2[4 * q + 2] = (int)pk2(v2.y, v2.z);
                r2[4 * q + 4] = f2bf(v2.w);
                if (r >= 1 && r <= 64) {
                    f4v g = (v0 + v1 + v2) * kk;
                    *(f4v*)&gray[(size_t)n * HI * WI + (size_t)R * WI + 4 * tx0 + 4 * q] = g;
                }
            }
        }
    }
    // ---- pass 2: margin cols x=0 and x=65..67 (1 thread per row) ----
    if (tid < 204) {
        int c = (tid >= 136) ? 2 : (tid >= 68) ? 1 : 0;
        int r = tid - c * 68;
        int R = 4 * ty0 - 1 + r;
        bool rok = (unsigned)R < HI;
        const float* src = img + c * HI * WI + (size_t)R * WI;
        float lm = (rok && tx0 > 0) ? src[4 * tx0 - 1] : 0.0f;
        f4v hv = (f4v)0.0f;
        if (rok && tx0 < 48) hv = *(const f4v*)(src + 4 * tx0 + 64);
        short* row = &in_lds[(c * 68 + r) * IN_RS];
        row[0] = f2bf(lm);
        row[65] = f2bf(hv.x);
        *(int*)&row[66] = (int)pk2(hv.y, hv.z);
    }
    __syncthreads();

    // ---- main MFMA loop ----
    f4v acc[4][5];
#pragma unroll
    for (int a = 0; a < 4; ++a)
#pragma unroll
        for (int b = 0; b < 5; ++b) acc[a][b] = (f4v)0.0f;

#pragma unroll
    for (int c = 0; c < 3; ++c) {
#pragma unroll
        for (int kyg = 0; kyg < 2; ++kyg) {
            const int ky = kyg * 4 + lg;                     // 0..7 (7 = pad plane)
            const bfv8* wp = (const bfv8*)(wbf + ((c * 8 + ky) * 80 + lx) * 8);
            bfv8 B0 = wp[0];
            bfv8 B1 = wp[16];
            bfv8 B2 = wp[32];
            bfv8 B3 = wp[48];
            bfv8 B4 = wp[64];
            const short* ibase = &in_lds[c * (68 * IN_RS) + ky * IN_RS + 4 * lx];
#pragma unroll
            for (int mt = 0; mt < 4; ++mt) {
                bfv8 A = *(const ubfv8*)(ibase + (16 * w + 4 * mt) * IN_RS);
                acc[mt][0] = __builtin_amdgcn_mfma_f32_16x16x32_bf16(A, B0, acc[mt][0], 0, 0, 0);
                acc[mt][1] = __builtin_amdgcn_mfma_f32_16x16x32_bf16(A, B1, acc[mt][1], 0, 0, 0);
                acc[mt][2] = __builtin_amdgcn_mfma_f32_16x16x32_bf16(A, B2, acc[mt][2], 0, 0, 0);
                acc[mt][3] = __builtin_amdgcn_mfma_f32_16x16x32_bf16(A, B3, acc[mt][3], 0, 0, 0);
                acc[mt][4] = __builtin_amdgcn_mfma_f32_16x16x32_bf16(A, B4, acc[mt][4], 0, 0, 0);
            }
        }
    }

    // ---- epilogue: softmax stats. lane holds px x=(lg*4+q), filter lx+16nt ----
#pragma unroll
    for (int nt = 0; nt < 5; ++nt) {
        float m = -3.4e38f;
#pragma unroll
        for (int mt = 0; mt < 4; ++mt)
#pragma unroll
            for (int q = 0; q < 4; ++q) m = fmaxf(m, acc[mt][nt][q]);
        m = fmaxf(m, __shfl_xor(m, 16, 64));
        m = fmaxf(m, __shfl_xor(m, 32, 64));
        if (lg == 0) part_m[w][nt * 16 + lx] = m;
    }
    __syncthreads();
    if (tid < 80)
        Mf[tid] = fmaxf(fmaxf(part_m[0][tid], part_m[1][tid]),
                        fmaxf(part_m[2][tid], part_m[3][tid]));
    __syncthreads();

#pragma unroll
    for (int nt = 0; nt < 5; ++nt) {
        float M = Mf[nt * 16 + lx];
        float s = 0.0f, sx = 0.0f, sy = 0.0f;
#pragma unroll
        for (int mt = 0; mt < 4; ++mt) {
            float yv = (float)(ty0 + 4 * w + mt);
#pragma unroll
            for (int q = 0; q < 4; ++q) {
                float e = __expf(acc[mt][nt][q] - M);
                s += e;
                sx += e * (float)(tx0 + lg * 4 + q);
                sy += e * yv;
            }
        }
        s += __shfl_xor(s, 16, 64);  s += __shfl_xor(s, 32, 64);
        sx += __shfl_xor(sx, 16, 64); sx += __shfl_xor(sx, 32, 64);
        sy += __shfl_xor(sy, 16, 64); sy += __shfl_xor(sy, 32, 64);
        if (lg == 0) {
            part_s[w][nt * 16 + lx] = s;
            part_sx[w][nt * 16 + lx] = sx;
            part_sy[w][nt * 16 + lx] = sy;
        }
    }
    __syncthreads();
    if (tid < NP) {
        float S = part_s[0][tid] + part_s[1][tid] + part_s[2][tid] + part_s[3][tid];
        float SX = part_sx[0][tid] + part_sx[1][tid] + part_sx[2][tid] + part_sx[3][tid];
        float SY = part_sy[0][tid] + part_sy[1][tid] + part_sy[2][tid] + part_sy[3][tid];
        float4* o = (float4*)(stats + (((size_t)n * NP + tid) * NT + tile) * 4);
        *o = make_float4(Mf[tid], S, SX, SY);
    }
}

// ---------------------------------------------------------------------------
// Kernel 2: Lucas-Kanade + centroid, LDS-staged patches (R15, 99->76us) with
// R16 bank-geometry fix (PSTR 28->40, see PSTR comment).
// ---------------------------------------------------------------------------
__device__ __forceinline__ float bil(const float* __restrict__ img, float x, float y) {
    float x0f = floorf(x), y0f = floorf(y);
    float wx = x - x0f, wy = y - y0f;
    int x0 = (int)x0f, y0 = (int)y0f;
    int x0i = min(max(x0, 0), WI - 1);
    int x1i = min(x0i + 1, WI - 1);
    int y0i = min(max(y0, 0), HI - 1);
    int y1i = min(y0i + 1, HI - 1);
    float v00 = img[y0i * WI + x0i];
    float v01 = img[y0i * WI + x1i];
    float v10 = img[y1i * WI + x0i];
    float v11 = img[y1i * WI + x1i];
    return v00 * (1.0f - wx) * (1.0f - wy) + v01 * wx * (1.0f - wy)
         + v10 * (1.0f - wx) * wy + v11 * wx * wy;
}

__device__ __forceinline__ void centroid_of(const float* __restrict__ stats,
                                            int n, int j, int lane,
                                            float& cx, float& cy) {
    const float4* st = (const float4*)(stats + (((size_t)n * NP + j) * NT) * 4);
    float4 v = st[lane & 15];
    float M = v.x, S = v.y, SX = v.z, SY = v.w;
#pragma unroll
    for (int d = 1; d < 16; d <<= 1) {
        float Mo = __shfl_xor(M, d, 64);
        float So = __shfl_xor(S, d, 64);
        float Xo = __shfl_xor(SX, d, 64);
        float Yo = __shfl_xor(SY, d, 64);
        float M2 = fmaxf(M, Mo);
        float e0 = __expf(M - M2);
        float e1 = __expf(Mo - M2);
        S = S * e0 + So * e1;
        SX = SX * e0 + Xo * e1;
        SY = SY * e0 + Yo * e1;
        M = M2;
    }
    cx = SX / S * 4.0f;
    cy = SY / S * 4.0f;
}

__device__ void lk_track(float* __restrict__ P,
                         const float* __restrict__ I, const float* __restrict__ J,
                         int lane, float x, float y, float& ox_, float& oy_) {
    int rowoff[5], loff[5];
    float Gx[5], Gy[5];
#pragma unroll
    for (int i = 0; i < 5; ++i) {
        int k = lane + 64 * i;
        int kk = (k < K_LK) ? k : 0;
        int dy = kk / 17, dx = kk % 17;
        rowoff[i] = dy * WI + dx;
        loff[i] = dy * PSTR + dx;
    }

    float ixf = floorf(x), iyf = floorf(y);
    int icx = (int)ixf, icy = (int)iyf;
    float wx = x - ixf, wy = y - iyf;
    float w00 = (1.0f - wx) * (1.0f - wy);
    float w01 = wx * (1.0f - wy);
    float w10 = (1.0f - wx) * wy;
    float w11 = wx * wy;

    int canJ = (icx >= 11) && (icx <= 243) && (icy >= 11) && (icy <= 243);
    canJ = __builtin_amdgcn_readfirstlane(canJ);

    float a11 = 0.0f, a12 = 0.0f, a22 = 0.0f, gxt = 0.0f, gyt = 0.0f;
    if (canJ) {
        // ---- stage I 20x20 at (icx-9, icy-9), stride PSTR ----
        {
            const float* src = I + (icy - 9) * WI + (icx - 9);
#pragma unroll
            for (int p = 0; p < 2; ++p) {
                int idx = lane + 64 * p;
                if (idx < 100) {
                    int row = idx / 5, cq = idx - row * 5;
                    *(f4v*)&P[row * PSTR + 4 * cq] = *(const uf4*)(src + row * WI + 4 * cq);
                }
            }
        }
        asm volatile("s_waitcnt lgkmcnt(0) vmcnt(0)" ::: "memory");
        // setup from LDS: sample (dy,dx) local base = (PSTR+1) + loff
#pragma unroll
        for (int i = 0; i < 5; ++i) {
            const float* pb = P + (PSTR + 1) + loff[i];
            float r0x = pb[-1], r0y = pb[0], r0z = pb[1], r0w = pb[2];
            float r1x = pb[PSTR - 1], r1y = pb[PSTR], r1z = pb[PSTR + 1], r1w = pb[PSTR + 2];
            float rmx = pb[-PSTR], rmy = pb[-PSTR + 1];
            float r2x = pb[2 * PSTR], r2y = pb[2 * PSTR + 1];
            float t   = w00 * r0y + w01 * r0z + w10 * r1y + w11 * r1z;
            float tx1 = w00 * r0z + w01 * r0w + w10 * r1z + w11 * r1w;
            float txm = w00 * r0x + w01 * r0y + w10 * r1x + w11 * r1y;
            float typ = w00 * r1y + w01 * r1z + w10 * r2x + w11 * r2y;
            float tym = w00 * rmx + w01 * rmy + w10 * r0y + w11 * r0z;
            float gx = 0.5f * (tx1 - txm);
            float gy = 0.5f * (typ - tym);
            if (i == 4 && lane >= 33) { t = 0.0f; gx = 0.0f; gy = 0.0f; }
            Gx[i] = gx; Gy[i] = gy;
            gxt = fmaf(gx, t, gxt); gyt = fmaf(gy, t, gyt);
            a11 = fmaf(gx, gx, a11); a12 = fmaf(gx, gy, a12); a22 = fmaf(gy, gy, a22);
        }
        // ---- restage with J 24x24 at (icx-11, icy-11) ----
        asm volatile("s_waitcnt lgkmcnt(0)" ::: "memory");
        {
            const float* srj = J + (icy - 11) * WI + (icx - 11);
#pragma unroll
            for (int p = 0; p < 3; ++p) {
                int idx = lane + 64 * p;
                if (idx < 144) {
                    int row = idx / 6, cq = idx - row * 6;
                    *(f4v*)&P[row * PSTR + 4 * cq] = *(const uf4*)(srj + row * WI + 4 * cq);
                }
            }
        }
        asm volatile("s_waitcnt lgkmcnt(0) vmcnt(0)" ::: "memory");
    } else {
        // ---- exact bil fallback setup (boundary tracks) ----
#pragma unroll
        for (int i = 0; i < 5; ++i) {
            int k = lane + 64 * i;
            bool v_ = (k < K_LK);
            int kk = v_ ? k : 0;
            float fx = x + (float)(kk % 17 - 8);
            float fy = y + (float)(kk / 17 - 8);
            float t = bil(I, fx, fy);
            float gx = (bil(I, fx + 1.0f, fy) - bil(I, fx - 1.0f, fy)) * 0.5f;
            float gy = (bil(I, fx, fy + 1.0f) - bil(I, fx, fy - 1.0f)) * 0.5f;
            if (!v_) { t = 0.0f; gx = 0.0f; gy = 0.0f; }
            Gx[i] = gx; Gy[i] = gy;
            gxt = fmaf(gx, t, gxt); gyt = fmaf(gy, t, gyt);
            a11 = fmaf(gx, gx, a11); a12 = fmaf(gx, gy, a12); a22 = fmaf(gy, gy, a22);
        }
    }
    a11 = rl63(wave_sum64(a11)) + 1e-6f;
    a12 = rl63(wave_sum64(a12));
    a22 = rl63(wave_sum64(a22)) + 1e-6f;
    float S_GxT = rl63(wave_sum64(gxt));
    float S_GyT = rl63(wave_sum64(gyt));
    float det = a11 * a22 - a12 * a12;
    float i11 = a22 / det, i12 = -a12 / det, i22 = a11 / det;

    float px = x, py = y;
#pragma unroll 1
    for (int s = 0; s < 10; ++s) {
        float bxv = 0.0f, byv = 0.0f;
        float jxf = floorf(px), jyf = floorf(py);
        float vx = px - jxf, vy = py - jyf;
        float u00 = (1.0f - vx) * (1.0f - vy);
        float u01 = vx * (1.0f - vy);
        float u10 = (1.0f - vx) * vy;
        float u11 = vx * vy;
        int jx = (int)jxf, jy = (int)jyf;
        int inWin = canJ && ((unsigned)(jx - icx + 3) <= 6u)
                         && ((unsigned)(jy - icy + 3) <= 6u);
        inWin = __builtin_amdgcn_readfirstlane(inWin);
        if (inWin) {
            int sb = (jy - icy + 3) * PSTR + (jx - icx + 3);
#pragma unroll
            for (int i = 0; i < 5; ++i) {
                const float* pb = P + sb + loff[i];
                float v = u00 * pb[0] + u01 * pb[1] + u10 * pb[PSTR] + u11 * pb[PSTR + 1];
                bxv = fmaf(Gx[i], v, bxv);           // invalid slots: G==0 kills it
                byv = fmaf(Gy[i], v, byv);
            }
        } else {
            int fastJ = (jxf >= 8.0f) && (jxf <= 246.0f) && (jyf >= 8.0f) && (jyf <= 246.0f);
            fastJ = __builtin_amdgcn_readfirstlane(fastJ);
            if (fastJ) {
                int jbase = __builtin_amdgcn_readfirstlane((jy - 8) * WI + jx - 8);
                const float* Jb = J + jbase;
#pragma unroll
                for (int i = 0; i < 5; ++i) {
                    const float* p = Jb + rowoff[i];
                    f2v q0 = *(const uf2*)(p);
                    f2v q1 = *(const uf2*)(p + WI);
                    float v = u00 * q0.x + u01 * q0.y + u10 * q1.x + u11 * q1.y;
                    bxv = fmaf(Gx[i], v, bxv);
                    byv = fmaf(Gy[i], v, byv);
                }
            } else {
#pragma unroll
                for (int i = 0; i < 5; ++i) {
                    int k = lane + 64 * i;
                    int kk = (k < K_LK) ? k : 0;
                    float v = bil(J, px + (float)(kk % 17 - 8), py + (float)(kk / 17 - 8));
                    bxv = fmaf(Gx[i], v, bxv);
                    byv = fmaf(Gy[i], v, byv);
                }
            }
        }
        float bxs = S_GxT - rl63(wave_sum64(bxv));
        float bys = S_GyT - rl63(wave_sum64(byv));
        px = fmaf(i11, bxs, fmaf(i12, bys, px));
        py = fmaf(i12, bxs, fmaf(i22, bys, py));
    }
    ox_ = px;
    oy_ = py;
}

__global__ __launch_bounds__(256) void k_lk(const float* __restrict__ gray,
                                            const float* __restrict__ stats,
                                            float* __restrict__ locs,
                                            float* __restrict__ out_next,
                                            float* __restrict__ out_fb,
                                            float* __restrict__ out_back) {
    __shared__ float patch[4][24 * PSTR];            // 15360 B: per-wave 24x40 f32
    float* P = patch[threadIdx.x >> 6];
    int wid = blockIdx.x * 4 + (threadIdx.x >> 6);   // 4 independent tasks/block
    int lane = threadIdx.x & 63;
    int variant = wid / (NPAIR * NP);
    int r = wid - variant * (NPAIR * NP);
    int pr = r / NP;
    int j = r - pr * NP;
    int b = pr / 15;
    int t = pr - b * 15;
    int n0 = b * 16 + t;
    const float* I = gray + (size_t)n0 * HI * WI;
    const float* J = gray + (size_t)(n0 + 1) * HI * WI;
    int o = (pr * NP + j) * 2;
    if (variant == 0) {
        float x, y;
        centroid_of(stats, n0, j, lane, x, y);
        if (lane == 0) { locs[(n0 * NP + j) * 2] = x; locs[(n0 * NP + j) * 2 + 1] = y; }
        float nx, ny;
        lk_track(P, I, J, lane, x, y, nx, ny);
        if (lane == 0) { out_next[o] = nx; out_next[o + 1] = ny; }
        float fx, fy;
        lk_track(P, J, I, lane, nx, ny, fx, fy);
        if (lane == 0) { out_fb[o] = fx; out_fb[o + 1] = fy; }
    } else {
        float x, y;
        centroid_of(stats, n0 + 1, j, lane, x, y);
        if (lane == 0) {
            locs[((n0 + 1) * NP + j) * 2] = x;
            locs[((n0 + 1) * NP + j) * 2 + 1] = y;
        }
        float bx, by;
        lk_track(P, J, I, lane, x, y, bx, by);
        if (lane == 0) { out_back[o] = bx; out_back[o + 1] = by; }
    }
}

// ---------------------------------------------------------------------------
extern "C" void kernel_launch(void* const* d_in, const int* in_sizes, int n_in,
                              void* d_out, int out_size, void* d_ws, size_t ws_size,
                              hipStream_t stream) {
    const float* inputs = (const float*)d_in[0];
    const float* det_w  = (const float*)d_in[1];
    // det_b (d_in[2]) is softmax-shift-invariant -> unused
    float* out = (float*)d_out;

    float* gray  = (float*)d_ws;                                       // 32 MiB
    float* stats = (float*)((char*)d_ws + (size_t)NIMG * HI * WI * 4); // 2.2 MiB
    short* wbf   = (short*)((char*)d_ws + (size_t)NIMG * HI * WI * 4
                            + (size_t)NIMG * NP * NT * 4 * 4);         // 30 KiB

    float* locs   = out;                    // [8,16,68,2]
    float* next_p = out + 17408;
    float* fb_p   = out + 33728;
    float* back_p = out + 50048;

    hipLaunchKernelGGL(k_wprep, dim3(16), dim3(256), 0, stream, det_w, wbf);
    hipLaunchKernelGGL(k_convgray, dim3(NCONVB), dim3(256), 0, stream,
                       inputs, wbf, stats, gray);
    hipLaunchKernelGGL(k_lk, dim3(NTASK / 4), dim3(256), 0, stream,
                       gray, stats, locs, next_p, fb_p, back_p);
}

// Round 17
// 115.457 us; speedup vs baseline: 1.1219x; 1.1219x over previous
//
#include <hip/hip_runtime.h>
#include <math.h>

#define HI 256
#define WI 256
#define NIMG 128          // B*S
#define NP 68             // landmarks
#define NT 16             // 4x4 tiles of 16x16 outputs per 64x64 heatmap
#define NPAIR 120         // B*(S-1)
#define K_LK 289          // 17x17 window
#define NCONVB (NT * NIMG)   // 2048 conv blocks (gray fused in)
#define NTASK (2 * NPAIR * NP)   // 16320 LK tasks
// LK LDS patch row stride (floats). LDS runs wave64 as TWO 32-lane phases
// (m136: 2-way free) -> analyze banks per half-wave. Sample addr = dy*PSTR+dx
// with kk=17dy+dx; PSTR==17 (mod 32) makes addr==kk==lane (mod 32): every
// lane in a half-wave hits a DISTINCT bank for every sample read (and the
// +-1/+-PSTR shifted reads are uniform rotations -> also conflict-free).
// R15 (28): 1.22e7 conflict cyc; R16 (40): 2.12e7 (3-way per half). 49==17.
// Odd stride costs 16B alignment on staging writes (b128 -> b32 pairs):
// ~15 write instrs vs ~260 now-conflict-free reads per track.
#define PSTR 49

typedef float f4v __attribute__((ext_vector_type(4)));
typedef float f2v __attribute__((ext_vector_type(2)));
typedef f4v __attribute__((aligned(4))) uf4;
typedef f2v __attribute__((aligned(4))) uf2;

typedef short bfv8 __attribute__((ext_vector_type(8)));   // 8 bf16 (MFMA frag)
typedef bfv8 __attribute__((aligned(8))) ubfv8;           // 8B-aligned LDS view

#define WBF_ELEMS (3 * 8 * 80 * 8)   // bf16 weight image [c][ky0..7][f0..79][kx0..7]

__device__ __forceinline__ short f2bf(float x) {
    unsigned u = __builtin_bit_cast(unsigned, x);
    u += 0x7fffu + ((u >> 16) & 1u);          // round-to-nearest-even
    return (short)(u >> 16);
}
__device__ __forceinline__ unsigned pk2(float lo, float hi) {
    return (unsigned)(unsigned short)f2bf(lo) | ((unsigned)(unsigned short)f2bf(hi) << 16);
}

// ---- DPP wave-64 sum; lane 63 holds the total (6 VALU ops, no LDS round-trip)
#define DPPA(ctrl, rm)                                                          \
    {                                                                           \
        int m_ = __builtin_amdgcn_update_dpp(0, __builtin_bit_cast(int, x),     \
                                             ctrl, rm, 0xf, true);              \
        x += __builtin_bit_cast(float, m_);                                     \
    }
__device__ __forceinline__ float wave_sum64(float x) {
    DPPA(0x111, 0xf)   // row_shr:1
    DPPA(0x112, 0xf)   // row_shr:2
    DPPA(0x114, 0xf)   // row_shr:4
    DPPA(0x118, 0xf)   // row_shr:8
    DPPA(0x142, 0xa)   // row_bcast:15 -> rows 1,3
    DPPA(0x143, 0xc)   // row_bcast:31 -> rows 2,3
    return x;          // lane 63 = total
}
__device__ __forceinline__ float rl63(float x) {
    return __builtin_bit_cast(float,
        __builtin_amdgcn_readlane(__builtin_bit_cast(int, x), 63));
}

// ---------------------------------------------------------------------------
// Kernel 0: weight prep -> bf16 [c][ky(8)][p(80)][kx(8)], pads zero. Grid 16.
// ---------------------------------------------------------------------------
__global__ __launch_bounds__(256) void k_wprep(const float* __restrict__ dw,
                                               short* __restrict__ wbf) {
    for (int ii = blockIdx.x * 256 + threadIdx.x; ii < WBF_ELEMS / 2;
         ii += 16 * 256) {
        int s0 = 2 * ii;                 // short index, kx = s0 & 7 (even)
        int kx = s0 & 7;
        int rest = s0 >> 3;              // (c*8+ky)*80 + p
        int p = rest % 80;
        int cky = rest / 80;             // c*8+ky
        int c = cky >> 3;
        int ky = cky & 7;
        unsigned lo = 0, hi = 0;
        if (ky < 7 && p < NP) {
            const float* wp = dw + p * 147 + (c * 7 + ky) * 7;
            lo = (unsigned short)f2bf(wp[kx]);
            if (kx + 1 < 7) hi = (unsigned short)f2bf(wp[kx + 1]);
        }
        ((int*)wbf)[ii] = (int)(lo | (hi << 16));
    }
}

// ---------------------------------------------------------------------------
// Kernel 1: conv 7x7/s4 MFMA + softmax stats, WITH gray fused into staging.
// ---------------------------------------------------------------------------
#define IN_RS 72                     // LDS input row stride (shorts), 144B
__global__ __launch_bounds__(256, 3) void k_convgray(const float* __restrict__ in,
                                                     const short* __restrict__ wbf,
                                                     float* __restrict__ stats,
                                                     float* __restrict__ gray) {
    const int bid = blockIdx.x;
    const int tile = bid & 15;
    const int n = bid >> 4;
    const int ty0 = (tile >> 2) * 16;
    const int tx0 = (tile & 3) * 16;
    const int tid = threadIdx.x;
    const int w = __builtin_amdgcn_readfirstlane(tid >> 6);   // wave: rows 4w..4w+3
    const int lane = tid & 63;
    const int lx = lane & 15;        // pixel x (A) / filter (B)
    const int lg = lane >> 4;        // k-group

    __shared__ short in_lds[3 * 68 * IN_RS];    // 29376 B bf16, x = C-(4tx0-1)
    __shared__ float part_m[4][80];
    __shared__ float Mf[80];
    __shared__ float part_s[4][80], part_sx[4][80], part_sy[4][80];

    const float* img = in + (size_t)n * 3 * HI * WI;
    const float kk = 1.0f / 3.0f;

    // ---- pass 1: main cols x=1..64, 3 channels/row, + gray core write ----
    {
        const int q = lane & 15;
        const int rsub = lane >> 4;
#pragma unroll
        for (int rr = 0; rr < 5; ++rr) {
            int r = rr * 16 + w * 4 + rsub;       // 0..79
            if (r < 68) {
                int R = 4 * ty0 - 1 + r;
                f4v v0 = (f4v)0.0f, v1 = (f4v)0.0f, v2 = (f4v)0.0f;
                if ((unsigned)R < HI) {
                    const float* s = img + (size_t)R * WI + 4 * tx0 + 4 * q;
                    v0 = *(const f4v*)(s);
                    v1 = *(const f4v*)(s + HI * WI);
                    v2 = *(const f4v*)(s + 2 * HI * WI);
                }
                short* r0 = &in_lds[r * IN_RS];
                r0[4 * q + 1] = f2bf(v0.x);
                *(int*)&r0[4 * q + 2] = (int)pk2(v0.y, v0.z);
                r0[4 * q + 4] = f2bf(v0.w);
                short* r1 = &in_lds[(68 + r) * IN_RS];
                r1[4 * q + 1] = f2bf(v1.x);
                *(int*)&r1[4 * q + 2] = (int)pk2(v1.y, v1.z);
                r1[4 * q + 4] = f2bf(v1.w);
                short* r2 = &in_lds[(136 + r) * IN_RS];
                r2[4 * q + 1] = f2bf(v2.x);
                *(int*)&r2[4 * q + 2] = (int)pk2(v2.y, v2.z);
                r2[4 * q + 4] = f2bf(v2.w);
                if (r >= 1 && r <= 64) {
                    f4v g = (v0 + v1 + v2) * kk;
                    *(f4v*)&gray[(size_t)n * HI * WI + (size_t)R * WI + 4 * tx0 + 4 * q] = g;
                }
            }
        }
    }
    // ---- pass 2: margin cols x=0 and x=65..67 (1 thread per row) ----
    if (tid < 204) {
        int c = (tid >= 136) ? 2 : (tid >= 68) ? 1 : 0;
        int r = tid - c * 68;
        int R = 4 * ty0 - 1 + r;
        bool rok = (unsigned)R < HI;
        const float* src = img + c * HI * WI + (size_t)R * WI;
        float lm = (rok && tx0 > 0) ? src[4 * tx0 - 1] : 0.0f;
        f4v hv = (f4v)0.0f;
        if (rok && tx0 < 48) hv = *(const f4v*)(src + 4 * tx0 + 64);
        short* row = &in_lds[(c * 68 + r) * IN_RS];
        row[0] = f2bf(lm);
        row[65] = f2bf(hv.x);
        *(int*)&row[66] = (int)pk2(hv.y, hv.z);
    }
    __syncthreads();

    // ---- main MFMA loop ----
    f4v acc[4][5];
#pragma unroll
    for (int a = 0; a < 4; ++a)
#pragma unroll
        for (int b = 0; b < 5; ++b) acc[a][b] = (f4v)0.0f;

#pragma unroll
    for (int c = 0; c < 3; ++c) {
#pragma unroll
        for (int kyg = 0; kyg < 2; ++kyg) {
            const int ky = kyg * 4 + lg;                     // 0..7 (7 = pad plane)
            const bfv8* wp = (const bfv8*)(wbf + ((c * 8 + ky) * 80 + lx) * 8);
            bfv8 B0 = wp[0];
            bfv8 B1 = wp[16];
            bfv8 B2 = wp[32];
            bfv8 B3 = wp[48];
            bfv8 B4 = wp[64];
            const short* ibase = &in_lds[c * (68 * IN_RS) + ky * IN_RS + 4 * lx];
#pragma unroll
            for (int mt = 0; mt < 4; ++mt) {
                bfv8 A = *(const ubfv8*)(ibase + (16 * w + 4 * mt) * IN_RS);
                acc[mt][0] = __builtin_amdgcn_mfma_f32_16x16x32_bf16(A, B0, acc[mt][0], 0, 0, 0);
                acc[mt][1] = __builtin_amdgcn_mfma_f32_16x16x32_bf16(A, B1, acc[mt][1], 0, 0, 0);
                acc[mt][2] = __builtin_amdgcn_mfma_f32_16x16x32_bf16(A, B2, acc[mt][2], 0, 0, 0);
                acc[mt][3] = __builtin_amdgcn_mfma_f32_16x16x32_bf16(A, B3, acc[mt][3], 0, 0, 0);
                acc[mt][4] = __builtin_amdgcn_mfma_f32_16x16x32_bf16(A, B4, acc[mt][4], 0, 0, 0);
            }
        }
    }

    // ---- epilogue: softmax stats. lane holds px x=(lg*4+q), filter lx+16nt ----
#pragma unroll
    for (int nt = 0; nt < 5; ++nt) {
        float m = -3.4e38f;
#pragma unroll
        for (int mt = 0; mt < 4; ++mt)
#pragma unroll
            for (int q = 0; q < 4; ++q) m = fmaxf(m, acc[mt][nt][q]);
        m = fmaxf(m, __shfl_xor(m, 16, 64));
        m = fmaxf(m, __shfl_xor(m, 32, 64));
        if (lg == 0) part_m[w][nt * 16 + lx] = m;
    }
    __syncthreads();
    if (tid < 80)
        Mf[tid] = fmaxf(fmaxf(part_m[0][tid], part_m[1][tid]),
                        fmaxf(part_m[2][tid], part_m[3][tid]));
    __syncthreads();

#pragma unroll
    for (int nt = 0; nt < 5; ++nt) {
        float M = Mf[nt * 16 + lx];
        float s = 0.0f, sx = 0.0f, sy = 0.0f;
#pragma unroll
        for (int mt = 0; mt < 4; ++mt) {
            float yv = (float)(ty0 + 4 * w + mt);
#pragma unroll
            for (int q = 0; q < 4; ++q) {
                float e = __expf(acc[mt][nt][q] - M);
                s += e;
                sx += e * (float)(tx0 + lg * 4 + q);
                sy += e * yv;
            }
        }
        s += __shfl_xor(s, 16, 64);  s += __shfl_xor(s, 32, 64);
        sx += __shfl_xor(sx, 16, 64); sx += __shfl_xor(sx, 32, 64);
        sy += __shfl_xor(sy, 16, 64); sy += __shfl_xor(sy, 32, 64);
        if (lg == 0) {
            part_s[w][nt * 16 + lx] = s;
            part_sx[w][nt * 16 + lx] = sx;
            part_sy[w][nt * 16 + lx] = sy;
        }
    }
    __syncthreads();
    if (tid < NP) {
        float S = part_s[0][tid] + part_s[1][tid] + part_s[2][tid] + part_s[3][tid];
        float SX = part_sx[0][tid] + part_sx[1][tid] + part_sx[2][tid] + part_sx[3][tid];
        float SY = part_sy[0][tid] + part_sy[1][tid] + part_sy[2][tid] + part_sy[3][tid];
        float4* o = (float4*)(stats + (((size_t)n * NP + tid) * NT + tile) * 4);
        *o = make_float4(Mf[tid], S, SX, SY);
    }
}

// ---------------------------------------------------------------------------
// Kernel 2: Lucas-Kanade + centroid, LDS-staged patches (R15, 99->76us),
// R17: conflict-free bank geometry via PSTR=49 (==17 mod 32, see PSTR note).
// ---------------------------------------------------------------------------
__device__ __forceinline__ float bil(const float* __restrict__ img, float x, float y) {
    float x0f = floorf(x), y0f = floorf(y);
    float wx = x - x0f, wy = y - y0f;
    int x0 = (int)x0f, y0 = (int)y0f;
    int x0i = min(max(x0, 0), WI - 1);
    int x1i = min(x0i + 1, WI - 1);
    int y0i = min(max(y0, 0), HI - 1);
    int y1i = min(y0i + 1, HI - 1);
    float v00 = img[y0i * WI + x0i];
    float v01 = img[y0i * WI + x1i];
    float v10 = img[y1i * WI + x0i];
    float v11 = img[y1i * WI + x1i];
    return v00 * (1.0f - wx) * (1.0f - wy) + v01 * wx * (1.0f - wy)
         + v10 * (1.0f - wx) * wy + v11 * wx * wy;
}

__device__ __forceinline__ void centroid_of(const float* __restrict__ stats,
                                            int n, int j, int lane,
                                            float& cx, float& cy) {
    const float4* st = (const float4*)(stats + (((size_t)n * NP + j) * NT) * 4);
    float4 v = st[lane & 15];
    float M = v.x, S = v.y, SX = v.z, SY = v.w;
#pragma unroll
    for (int d = 1; d < 16; d <<= 1) {
        float Mo = __shfl_xor(M, d, 64);
        float So = __shfl_xor(S, d, 64);
        float Xo = __shfl_xor(SX, d, 64);
        float Yo = __shfl_xor(SY, d, 64);
        float M2 = fmaxf(M, Mo);
        float e0 = __expf(M - M2);
        float e1 = __expf(Mo - M2);
        S = S * e0 + So * e1;
        SX = SX * e0 + Xo * e1;
        SY = SY * e0 + Yo * e1;
        M = M2;
    }
    cx = SX / S * 4.0f;
    cy = SY / S * 4.0f;
}

__device__ void lk_track(float* __restrict__ P,
                         const float* __restrict__ I, const float* __restrict__ J,
                         int lane, float x, float y, float& ox_, float& oy_) {
    int rowoff[5], loff[5];
    float Gx[5], Gy[5];
#pragma unroll
    for (int i = 0; i < 5; ++i) {
        int k = lane + 64 * i;
        int kk = (k < K_LK) ? k : 0;
        int dy = kk / 17, dx = kk % 17;
        rowoff[i] = dy * WI + dx;
        loff[i] = dy * PSTR + dx;
    }

    float ixf = floorf(x), iyf = floorf(y);
    int icx = (int)ixf, icy = (int)iyf;
    float wx = x - ixf, wy = y - iyf;
    float w00 = (1.0f - wx) * (1.0f - wy);
    float w01 = wx * (1.0f - wy);
    float w10 = (1.0f - wx) * wy;
    float w11 = wx * wy;

    int canJ = (icx >= 11) && (icx <= 243) && (icy >= 11) && (icy <= 243);
    canJ = __builtin_amdgcn_readfirstlane(canJ);

    float a11 = 0.0f, a12 = 0.0f, a22 = 0.0f, gxt = 0.0f, gyt = 0.0f;
    if (canJ) {
        // ---- stage I 20x20 at (icx-9, icy-9), stride PSTR (unaligned ok) ----
        {
            const float* src = I + (icy - 9) * WI + (icx - 9);
#pragma unroll
            for (int p = 0; p < 2; ++p) {
                int idx = lane + 64 * p;
                if (idx < 100) {
                    int row = idx / 5, cq = idx - row * 5;
                    *(uf4*)&P[row * PSTR + 4 * cq] = *(const uf4*)(src + row * WI + 4 * cq);
                }
            }
        }
        asm volatile("s_waitcnt lgkmcnt(0) vmcnt(0)" ::: "memory");
        // setup from LDS: sample (dy,dx) local base = (PSTR+1) + loff
#pragma unroll
        for (int i = 0; i < 5; ++i) {
            const float* pb = P + (PSTR + 1) + loff[i];
            float r0x = pb[-1], r0y = pb[0], r0z = pb[1], r0w = pb[2];
            float r1x = pb[PSTR - 1], r1y = pb[PSTR], r1z = pb[PSTR + 1], r1w = pb[PSTR + 2];
            float rmx = pb[-PSTR], rmy = pb[-PSTR + 1];
            float r2x = pb[2 * PSTR], r2y = pb[2 * PSTR + 1];
            float t   = w00 * r0y + w01 * r0z + w10 * r1y + w11 * r1z;
            float tx1 = w00 * r0z + w01 * r0w + w10 * r1z + w11 * r1w;
            float txm = w00 * r0x + w01 * r0y + w10 * r1x + w11 * r1y;
            float typ = w00 * r1y + w01 * r1z + w10 * r2x + w11 * r2y;
            float tym = w00 * rmx + w01 * rmy + w10 * r0y + w11 * r0z;
            float gx = 0.5f * (tx1 - txm);
            float gy = 0.5f * (typ - tym);
            if (i == 4 && lane >= 33) { t = 0.0f; gx = 0.0f; gy = 0.0f; }
            Gx[i] = gx; Gy[i] = gy;
            gxt = fmaf(gx, t, gxt); gyt = fmaf(gy, t, gyt);
            a11 = fmaf(gx, gx, a11); a12 = fmaf(gx, gy, a12); a22 = fmaf(gy, gy, a22);
        }
        // ---- restage with J 24x24 at (icx-11, icy-11) ----
        asm volatile("s_waitcnt lgkmcnt(0)" ::: "memory");
        {
            const float* srj = J + (icy - 11) * WI + (icx - 11);
#pragma unroll
            for (int p = 0; p < 3; ++p) {
                int idx = lane + 64 * p;
                if (idx < 144) {
                    int row = idx / 6, cq = idx - row * 6;
                    *(uf4*)&P[row * PSTR + 4 * cq] = *(const uf4*)(srj + row * WI + 4 * cq);
                }
            }
        }
        asm volatile("s_waitcnt lgkmcnt(0) vmcnt(0)" ::: "memory");
    } else {
        // ---- exact bil fallback setup (boundary tracks) ----
#pragma unroll
        for (int i = 0; i < 5; ++i) {
            int k = lane + 64 * i;
            bool v_ = (k < K_LK);
            int kk = v_ ? k : 0;
            float fx = x + (float)(kk % 17 - 8);
            float fy = y + (float)(kk / 17 - 8);
            float t = bil(I, fx, fy);
            float gx = (bil(I, fx + 1.0f, fy) - bil(I, fx - 1.0f, fy)) * 0.5f;
            float gy = (bil(I, fx, fy + 1.0f) - bil(I, fx, fy - 1.0f)) * 0.5f;
            if (!v_) { t = 0.0f; gx = 0.0f; gy = 0.0f; }
            Gx[i] = gx; Gy[i] = gy;
            gxt = fmaf(gx, t, gxt); gyt = fmaf(gy, t, gyt);
            a11 = fmaf(gx, gx, a11); a12 = fmaf(gx, gy, a12); a22 = fmaf(gy, gy, a22);
        }
    }
    a11 = rl63(wave_sum64(a11)) + 1e-6f;
    a12 = rl63(wave_sum64(a12));
    a22 = rl63(wave_sum64(a22)) + 1e-6f;
    float S_GxT = rl63(wave_sum64(gxt));
    float S_GyT = rl63(wave_sum64(gyt));
    float det = a11 * a22 - a12 * a12;
    float i11 = a22 / det, i12 = -a12 / det, i22 = a11 / det;

    float px = x, py = y;
#pragma unroll 1
    for (int s = 0; s < 10; ++s) {
        float bxv = 0.0f, byv = 0.0f;
        float jxf = floorf(px), jyf = floorf(py);
        float vx = px - jxf, vy = py - jyf;
        float u00 = (1.0f - vx) * (1.0f - vy);
        float u01 = vx * (1.0f - vy);
        float u10 = (1.0f - vx) * vy;
        float u11 = vx * vy;
        int jx = (int)jxf, jy = (int)jyf;
        int inWin = canJ && ((unsigned)(jx - icx + 3) <= 6u)
                         && ((unsigned)(jy - icy + 3) <= 6u);
        inWin = __builtin_amdgcn_readfirstlane(inWin);
        if (inWin) {
            int sb = (jy - icy + 3) * PSTR + (jx - icx + 3);
#pragma unroll
            for (int i = 0; i < 5; ++i) {
                const float* pb = P + sb + loff[i];
                float v = u00 * pb[0] + u01 * pb[1] + u10 * pb[PSTR] + u11 * pb[PSTR + 1];
                bxv = fmaf(Gx[i], v, bxv);           // invalid slots: G==0 kills it
                byv = fmaf(Gy[i], v, byv);
            }
        } else {
            int fastJ = (jxf >= 8.0f) && (jxf <= 246.0f) && (jyf >= 8.0f) && (jyf <= 246.0f);
            fastJ = __builtin_amdgcn_readfirstlane(fastJ);
            if (fastJ) {
                int jbase = __builtin_amdgcn_readfirstlane((jy - 8) * WI + jx - 8);
                const float* Jb = J + jbase;
#pragma unroll
                for (int i = 0; i < 5; ++i) {
                    const float* p = Jb + rowoff[i];
                    f2v q0 = *(const uf2*)(p);
                    f2v q1 = *(const uf2*)(p + WI);
                    float v = u00 * q0.x + u01 * q0.y + u10 * q1.x + u11 * q1.y;
                    bxv = fmaf(Gx[i], v, bxv);
                    byv = fmaf(Gy[i], v, byv);
                }
            } else {
#pragma unroll
                for (int i = 0; i < 5; ++i) {
                    int k = lane + 64 * i;
                    int kk = (k < K_LK) ? k : 0;
                    float v = bil(J, px + (float)(kk % 17 - 8), py + (float)(kk / 17 - 8));
                    bxv = fmaf(Gx[i], v, bxv);
                    byv = fmaf(Gy[i], v, byv);
                }
            }
        }
        float bxs = S_GxT - rl63(wave_sum64(bxv));
        float bys = S_GyT - rl63(wave_sum64(byv));
        px = fmaf(i11, bxs, fmaf(i12, bys, px));
        py = fmaf(i12, bxs, fmaf(i22, bys, py));
    }
    ox_ = px;
    oy_ = py;
}

__global__ __launch_bounds__(256) void k_lk(const float* __restrict__ gray,
                                            const float* __restrict__ stats,
                                            float* __restrict__ locs,
                                            float* __restrict__ out_next,
                                            float* __restrict__ out_fb,
                                            float* __restrict__ out_back) {
    __shared__ float patch[4][24 * PSTR];            // 18816 B: per-wave 24x49 f32
    float* P = patch[threadIdx.x >> 6];
    int wid = blockIdx.x * 4 + (threadIdx.x >> 6);   // 4 independent tasks/block
    int lane = threadIdx.x & 63;
    int variant = wid / (NPAIR * NP);
    int r = wid - variant * (NPAIR * NP);
    int pr = r / NP;
    int j = r - pr * NP;
    int b = pr / 15;
    int t = pr - b * 15;
    int n0 = b * 16 + t;
    const float* I = gray + (size_t)n0 * HI * WI;
    const float* J = gray + (size_t)(n0 + 1) * HI * WI;
    int o = (pr * NP + j) * 2;
    if (variant == 0) {
        float x, y;
        centroid_of(stats, n0, j, lane, x, y);
        if (lane == 0) { locs[(n0 * NP + j) * 2] = x; locs[(n0 * NP + j) * 2 + 1] = y; }
        float nx, ny;
        lk_track(P, I, J, lane, x, y, nx, ny);
        if (lane == 0) { out_next[o] = nx; out_next[o + 1] = ny; }
        float fx, fy;
        lk_track(P, J, I, lane, nx, ny, fx, fy);
        if (lane == 0) { out_fb[o] = fx; out_fb[o + 1] = fy; }
    } else {
        float x, y;
        centroid_of(stats, n0 + 1, j, lane, x, y);
        if (lane == 0) {
            locs[((n0 + 1) * NP + j) * 2] = x;
            locs[((n0 + 1) * NP + j) * 2 + 1] = y;
        }
        float bx, by;
        lk_track(P, J, I, lane, x, y, bx, by);
        if (lane == 0) { out_back[o] = bx; out_back[o + 1] = by; }
    }
}

// ---------------------------------------------------------------------------
extern "C" void kernel_launch(void* const* d_in, const int* in_sizes, int n_in,
                              void* d_out, int out_size, void* d_ws, size_t ws_size,
                              hipStream_t stream) {
    const float* inputs = (const float*)d_in[0];
    const float* det_w  = (const float*)d_in[1];
    // det_b (d_in[2]) is softmax-shift-invariant -> unused
    float* out = (float*)d_out;

    float* gray  = (float*)d_ws;                                       // 32 MiB
    float* stats = (float*)((char*)d_ws + (size_t)NIMG * HI * WI * 4); // 2.2 MiB
    short* wbf   = (short*)((char*)d_ws + (size_t)NIMG * HI * WI * 4
                            + (size_t)NIMG * NP * NT * 4 * 4);         // 30 KiB

    float* locs   = out;                    // [8,16,68,2]
    float* next_p = out + 17408;
    float* fb_p   = out + 33728;
    float* back_p = out + 50048;

    hipLaunchKernelGGL(k_wprep, dim3(16), dim3(256), 0, stream, det_w, wbf);
    hipLaunchKernelGGL(k_convgray, dim3(NCONVB), dim3(256), 0, stream,
                       inputs, wbf, stats, gray);
    hipLaunchKernelGGL(k_lk, dim3(NTASK / 4), dim3(256), 0, stream,
                       gray, stats, locs, next_p, fb_p, back_p);
}